// Round 2
// baseline (9.803 us; speedup 1.0000x reference)
//
#include <hip/hip_runtime.h>
#include <math.h>

// DistanceTransform (kornia-style) on (B=16, C=1, H=128, W=128) fp32.
//
// The reference's 128-iteration lax.scan provably reduces to iteration 0 only:
//   - boundary is pointwise monotone non-decreasing (values only replaced by 1,
//     image in (0,1)), and the 3x3 kernel has non-negative weights, so
//     conv(boundary) is monotone non-decreasing per pixel across iterations.
//   - a pixel contributes at iter i iff conv_i < 1 (cdt > 0). If it contributes
//     at i=0 its boundary becomes 1 -> conv >= 1 (center weight = exp(0) = 1)
//     forever -> never again. If conv_0 >= 1, monotonicity gives conv_i >= 1
//     forever -> never contributes.
//   - at i=0 the offset term is (0*3)//2 = 0.
// Hence: out = relu(-h * log(conv3x3_replicate(image))). Later iterations add
// exactly 0.0f (conv > 0 always -> cdt finite -> cdt * 0 == 0).
//
// R1: 4 pixels/thread (float4 load/store), fast log (v_log_f32). Kernel is
// launch-overhead bound (2 MB traffic = 0.33 us at 6.3 TB/s); this trims the
// execution tail only.

#define BATCH 16
#define HEIGHT 128
#define WIDTH 128
#define H_PARAM 0.35f

__global__ __launch_bounds__(256) void DistanceTransform_66683662238011_kernel(
    const float* __restrict__ img, float* __restrict__ out) {
    // one thread = one x-quad of 4 pixels
    const int idx = blockIdx.x * 256 + threadIdx.x;  // 0 .. 65535
    const int qx = idx & 31;            // 32 quads per row
    const int y  = (idx >> 5) & 127;
    const int b  = idx >> 12;
    const int x0 = qx << 2;

    const float* __restrict__ p = img + (b << 14);

    const int ym = (y > 0) ? y - 1 : 0;
    const int yp = (y < HEIGHT - 1) ? y + 1 : HEIGHT - 1;

    const int xl = (x0 > 0) ? x0 - 1 : 0;                       // replicate left
    const int xr = (x0 + 4 < WIDTH) ? x0 + 4 : WIDTH - 1;       // replicate right

    const float* rt = p + (ym << 7);
    const float* rm = p + (y  << 7);
    const float* rb = p + (yp << 7);

    // each row: 6 needed values [x0-1 .. x0+4] = 1 aligned float4 + 2 scalars
    float top[6], mid[6], bot[6];
    {
        const float4 t4 = *reinterpret_cast<const float4*>(rt + x0);
        top[0] = rt[xl]; top[1] = t4.x; top[2] = t4.y; top[3] = t4.z; top[4] = t4.w; top[5] = rt[xr];
        const float4 m4 = *reinterpret_cast<const float4*>(rm + x0);
        mid[0] = rm[xl]; mid[1] = m4.x; mid[2] = m4.y; mid[3] = m4.z; mid[4] = m4.w; mid[5] = rm[xr];
        const float4 b4 = *reinterpret_cast<const float4*>(rb + x0);
        bot[0] = rb[xl]; bot[1] = b4.x; bot[2] = b4.y; bot[3] = b4.z; bot[4] = b4.w; bot[5] = rb[xr];
    }

    // weights matching the reference's fp32 kernel construction
    const float w1 = expf(-1.0f / H_PARAM);
    const float w2 = expf(-sqrtf(2.0f) / H_PARAM);

    float4 o;
    float* op = &o.x;
#pragma unroll
    for (int j = 0; j < 4; ++j) {
        const float conv = mid[j + 1]
                         + w1 * (top[j + 1] + bot[j + 1] + mid[j] + mid[j + 2])
                         + w2 * (top[j] + top[j + 2] + bot[j] + bot[j + 2]);
        const float cdt = -H_PARAM * __logf(conv);  // v_log_f32-based fast log
        op[j] = (cdt > 0.0f) ? cdt : 0.0f;
    }

    *reinterpret_cast<float4*>(out + (idx << 2)) = o;
}

extern "C" void kernel_launch(void* const* d_in, const int* in_sizes, int n_in,
                              void* d_out, int out_size, void* d_ws, size_t ws_size,
                              hipStream_t stream) {
    const float* img = (const float*)d_in[0];
    float* out = (float*)d_out;
    const int total_quads = BATCH * HEIGHT * WIDTH / 4;  // 65536
    const int block = 256;
    const int grid = total_quads / block;  // 256
    DistanceTransform_66683662238011_kernel<<<grid, block, 0, stream>>>(img, out);
}